// Round 6
// baseline (98.943 us; speedup 1.0000x reference)
//
#include <hip/hip_runtime.h>

#define NA 2048
#define NT 256
#define QCAP 512   // per-atom neighbor-queue capacity; mean count ~17, P(>512) ~ 0

__device__ __forceinline__ float silu_f(float x) { return x / (1.0f + __expf(-x)); }

// butterfly: result valid in ALL lanes (no broadcast needed)
__device__ __forceinline__ float wave_allreduce(float v) {
    #pragma unroll
    for (int off = 32; off > 0; off >>= 1) v += __shfl_xor(v, off, 64);
    return v;
}

__device__ __forceinline__ float wave_reduce(float v) {
    #pragma unroll
    for (int off = 32; off > 0; off >>= 1) v += __shfl_down(v, off, 64);
    return v;
}

// ---------------------------------------------------------------------------
// k1: RBF features + both MLPs for TWO atoms per block (1024 blocks).
// Scan shares each pos[j] load between both atoms (halves load traffic and
// block count vs 1 atom/block). After the single queue barrier, each of the
// 4 waves owns one (atom, MLP) task: wv>>1 = atom, wv&1 = charge/energy.
// No further __syncthreads (per-wave LDS scratch; same-wave RAW is ordered
// by the compiler's lgkmcnt wait).
// ---------------------------------------------------------------------------
__global__ __launch_bounds__(NT) void k1_feat_mlp(
    const float* __restrict__ pos,
    const float* __restrict__ cw1, const float* __restrict__ cb1,
    const float* __restrict__ cw2, const float* __restrict__ cb2,
    const float* __restrict__ cw3, const float* __restrict__ cb3,
    const float* __restrict__ ew1, const float* __restrict__ eb1,
    const float* __restrict__ ew2, const float* __restrict__ eb2,
    const float* __restrict__ ew3, const float* __restrict__ eb3,
    float4* __restrict__ pxyzq, float* __restrict__ rawq, float* __restrict__ esr)
{
    __shared__ float qd[2][QCAP];
    __shared__ int qn[2];
    __shared__ float sh1[4][64];
    const int i0 = blockIdx.x * 2, i1 = i0 + 1;
    const int tid = threadIdx.x, lane = tid & 63, wv = tid >> 6;

    if (tid < 2) qn[tid] = 0;
    __syncthreads();

    const float p0x = pos[3*i0], p0y = pos[3*i0+1], p0z = pos[3*i0+2];
    const float p1x = pos[3*i1], p1y = pos[3*i1+1], p1z = pos[3*i1+2];

    // ---- scan: cheap distance test for both atoms, append hits to queues ----
    #pragma unroll
    for (int jj = 0; jj < NA / NT; ++jj) {
        const int j = tid + jj * NT;
        const float px = pos[3*j], py = pos[3*j+1], pz = pos[3*j+2];
        float dx0 = p0x - px, dy0 = p0y - py, dz0 = p0z - pz;
        float d20 = dx0*dx0 + dy0*dy0 + dz0*dz0;
        if (d20 > 0.0f && d20 < 25.0f) {
            int k = atomicAdd(&qn[0], 1);   // LDS-scope atomic: cheap
            if (k < QCAP) qd[0][k] = d20;
        }
        float dx1 = p1x - px, dy1 = p1y - py, dz1 = p1z - pz;
        float d21 = dx1*dx1 + dy1*dy1 + dz1*dz1;
        if (d21 > 0.0f && d21 < 25.0f) {
            int k = atomicAdd(&qn[1], 1);
            if (k < QCAP) qd[1][k] = d21;
        }
    }
    __syncthreads();   // queues complete — LAST barrier in this kernel

    // ---- each wave: one (atom, MLP) task ----
    const int atom = wv >> 1;          // 0 -> i0, 1 -> i1
    const int mlp  = wv & 1;           // 0 -> charge MLP, 1 -> energy MLP
    const int i    = atom ? i1 : i0;
    const float pix = atom ? p1x : p0x;
    const float piy = atom ? p1y : p0y;
    const float piz = atom ? p1z : p0z;

    const int n = qn[atom] < QCAP ? qn[atom] : QCAP;
    float acc[16];
    #pragma unroll
    for (int r = 0; r < 16; ++r) acc[r] = 0.0f;
    for (int k = lane; k < n; k += 64) {
        float d  = sqrtf(qd[atom][k]);
        float sm = 0.5f * (1.0f + __cosf(0.6283185307179586f * d)); // cos(pi*d/5)
        #pragma unroll
        for (int r = 0; r < 16; ++r) {
            float t = d - (0.5f + 0.3f * (float)r);   // centers linspace(0.5,5,16)
            acc[r] += sm * __expf(-t * t * 25.28395061728395f); // 1/(2*eta^2)
        }
    }

    const float* w1 = mlp ? ew1 : cw1;
    const float* b1 = mlp ? eb1 : cb1;
    const float* w2 = mlp ? ew2 : cw2;
    const float* b2 = mlp ? eb2 : cb2;
    const float* w3 = mlp ? ew3 : cw3;
    const float* b3 = mlp ? eb3 : cb3;

    // fused feature-allreduce + layer 1 (features land in all lanes)
    float s = b1[lane];
    #pragma unroll
    for (int r = 0; r < 16; ++r) {
        float f = wave_allreduce(acc[r]);
        s += f * w1[r * 64 + lane];
    }
    sh1[wv][lane] = silu_f(s);
    // same-wave LDS RAW: ordered by lgkmcnt, no barrier needed (per-wave scratch)
    float s2 = b2[lane];
    #pragma unroll 8
    for (int k = 0; k < 64; ++k) s2 += sh1[wv][k] * w2[k * 64 + lane];
    float p = silu_f(s2) * w3[lane];
    p = wave_reduce(p);

    if (lane == 0) {
        float o = p + b3[0];
        if (mlp == 0) { rawq[i] = o; pxyzq[i] = make_float4(pix, piy, piz, o); }
        else          { esr[i] = o; }
    }
}

// ---------------------------------------------------------------------------
// k2: pair pass with RAW charges, FOUR atoms per block (512 blocks).
// Each loaded pj serves 4 accumulator pairs. s_i = sum' qr_j/r_ij,
// t_i = sum' 1/r_ij.
// ---------------------------------------------------------------------------
__global__ __launch_bounds__(NT) void k2_pair(const float4* __restrict__ pxyzq,
                                              float* __restrict__ sarr,
                                              float* __restrict__ tarr)
{
    __shared__ float ws[4][8];
    const int ib = blockIdx.x * 4;
    const int tid = threadIdx.x, lane = tid & 63, wv = tid >> 6;
    const float4 p0 = pxyzq[ib+0];
    const float4 p1 = pxyzq[ib+1];
    const float4 p2 = pxyzq[ib+2];
    const float4 p3 = pxyzq[ib+3];
    float s0 = 0, t0 = 0, s1 = 0, t1 = 0, s2 = 0, t2 = 0, s3 = 0, t3 = 0;
    #pragma unroll
    for (int jj = 0; jj < NA / NT; ++jj) {
        const int j = tid + jj * NT;
        const float4 pj = pxyzq[j];
        {
            float dx = p0.x - pj.x, dy = p0.y - pj.y, dz = p0.z - pj.z;
            float d2 = dx*dx + dy*dy + dz*dz;
            if (j != ib+0) { float r = rsqrtf(d2); t0 += r; s0 += pj.w * r; }
        }
        {
            float dx = p1.x - pj.x, dy = p1.y - pj.y, dz = p1.z - pj.z;
            float d2 = dx*dx + dy*dy + dz*dz;
            if (j != ib+1) { float r = rsqrtf(d2); t1 += r; s1 += pj.w * r; }
        }
        {
            float dx = p2.x - pj.x, dy = p2.y - pj.y, dz = p2.z - pj.z;
            float d2 = dx*dx + dy*dy + dz*dz;
            if (j != ib+2) { float r = rsqrtf(d2); t2 += r; s2 += pj.w * r; }
        }
        {
            float dx = p3.x - pj.x, dy = p3.y - pj.y, dz = p3.z - pj.z;
            float d2 = dx*dx + dy*dy + dz*dz;
            if (j != ib+3) { float r = rsqrtf(d2); t3 += r; s3 += pj.w * r; }
        }
    }
    s0 = wave_reduce(s0); t0 = wave_reduce(t0);
    s1 = wave_reduce(s1); t1 = wave_reduce(t1);
    s2 = wave_reduce(s2); t2 = wave_reduce(t2);
    s3 = wave_reduce(s3); t3 = wave_reduce(t3);
    if (lane == 0) {
        ws[wv][0] = s0; ws[wv][1] = t0; ws[wv][2] = s1; ws[wv][3] = t1;
        ws[wv][4] = s2; ws[wv][5] = t2; ws[wv][6] = s3; ws[wv][7] = t3;
    }
    __syncthreads();
    if (tid < 8) {
        float v = ws[0][tid] + ws[1][tid] + ws[2][tid] + ws[3][tid];
        const int a = ib + (tid >> 1);
        if ((tid & 1) == 0) sarr[a] = v;
        else                tarr[a] = v;
    }
}

// ---------------------------------------------------------------------------
// k3: final reduction + correction + outputs.
// E_lr = 0.5*(S_qq + c*(A + B) + c^2*S_11), c = -sum(qr)/N
//   S_qq = sum qr_i s_i, A = sum qr_i t_i, B = sum s_i, S_11 = sum t_i
// ---------------------------------------------------------------------------
__global__ __launch_bounds__(NT) void k3_final(const float* __restrict__ rawq,
                                               const float* __restrict__ esr,
                                               const float* __restrict__ sarr,
                                               const float* __restrict__ tarr,
                                               float* __restrict__ out)
{
    __shared__ float wred[4][6];
    __shared__ float sc;
    const int tid = threadIdx.x, lane = tid & 63, wv = tid >> 6;
    float pq = 0, pe = 0, pqq = 0, pqt = 0, ps = 0, pt = 0;
    for (int i = tid; i < NA; i += NT) {
        float q = rawq[i], s = sarr[i], t = tarr[i];
        pq += q; pe += esr[i]; pqq += q * s; pqt += q * t; ps += s; pt += t;
    }
    pq  = wave_reduce(pq);  pe = wave_reduce(pe);  pqq = wave_reduce(pqq);
    pqt = wave_reduce(pqt); ps = wave_reduce(ps);  pt  = wave_reduce(pt);
    if (lane == 0) {
        wred[wv][0] = pq; wred[wv][1] = pe; wred[wv][2] = pqq;
        wred[wv][3] = pqt; wred[wv][4] = ps; wred[wv][5] = pt;
    }
    __syncthreads();
    if (tid == 0) {
        float q  = wred[0][0] + wred[1][0] + wred[2][0] + wred[3][0];
        float e  = wred[0][1] + wred[1][1] + wred[2][1] + wred[3][1];
        float qq = wred[0][2] + wred[1][2] + wred[2][2] + wred[3][2];
        float qt = wred[0][3] + wred[1][3] + wred[2][3] + wred[3][3];
        float ss = wred[0][4] + wred[1][4] + wred[2][4] + wred[3][4];
        float tt = wred[0][5] + wred[1][5] + wred[2][5] + wred[3][5];
        float c = -q * (1.0f / (float)NA);
        sc = c;
        out[0] = 0.5f * (qq + c * (qt + ss) + c * c * tt) + e;
    }
    __syncthreads();
    const float c = sc;
    for (int i = tid; i < NA; i += NT) out[1 + i] = rawq[i] + c;
}

extern "C" void kernel_launch(void* const* d_in, const int* in_sizes, int n_in,
                              void* d_out, int out_size, void* d_ws, size_t ws_size,
                              hipStream_t stream) {
    const float* pos = (const float*)d_in[0];
    const float* cw1 = (const float*)d_in[1];
    const float* cb1 = (const float*)d_in[2];
    const float* cw2 = (const float*)d_in[3];
    const float* cb2 = (const float*)d_in[4];
    const float* cw3 = (const float*)d_in[5];
    const float* cb3 = (const float*)d_in[6];
    const float* ew1 = (const float*)d_in[7];
    const float* eb1 = (const float*)d_in[8];
    const float* ew2 = (const float*)d_in[9];
    const float* eb2 = (const float*)d_in[10];
    const float* ew3 = (const float*)d_in[11];
    const float* eb3 = (const float*)d_in[12];
    float* out = (float*)d_out;

    // workspace layout (all written before read within one replay -> poison-safe)
    float4* pxyzq = (float4*)d_ws;                  // 2048 float4
    float*  rawq  = (float*)(pxyzq + NA);           // 2048
    float*  esr   = rawq + NA;                      // 2048
    float*  sarr  = esr + NA;                       // 2048
    float*  tarr  = sarr + NA;                      // 2048

    k1_feat_mlp<<<NA / 2, NT, 0, stream>>>(pos,
                                           cw1, cb1, cw2, cb2, cw3, cb3,
                                           ew1, eb1, ew2, eb2, ew3, eb3,
                                           pxyzq, rawq, esr);
    k2_pair<<<NA / 4, NT, 0, stream>>>(pxyzq, sarr, tarr);
    k3_final<<<1, NT, 0, stream>>>(rawq, esr, sarr, tarr, out);
}